// Round 12
// baseline (280.206 us; speedup 1.0000x reference)
//
#include <hip/hip_runtime.h>
#include <cstdint>
#include <cstddef>

// [B,H,N,Dh] = [4,16,2048,64]; out[b,h,m,d] = (sum_n softmax(QK^T)[n,m]) * v[b,h,m,d]
#define B_    4
#define H_    16
#define N_    2048
#define D_    64
#define BH_   (B_*H_)
#define SCALE 0.125f
#define QSCL  0.18033688011f      // SCALE * log2(e)

#define NTC   16                  // streamed 64-row tiles per chunk (1024 rows)
#define TB64  8192                // bytes per 64-row bf16 tile
#define TILEB 16384               // image tile: 128 rows x 128 B
#define BHB   (16*TILEB)          // 256 KB per (bh, tensor)
#define QKB   ((size_t)2*BH_*BHB) // 32 MB image
#define NZW   (BH_*N_)            // 131072 floats (Z / CS / RI each)

typedef __attribute__((ext_vector_type(8))) short bf16x8;
typedef __attribute__((ext_vector_type(4))) float f32x4;

#if __has_builtin(__builtin_amdgcn_exp2f)
#define EXP2(x) __builtin_amdgcn_exp2f(x)
#else
#define EXP2(x) exp2f(x)
#endif

#define BARRIER() do { asm volatile("" ::: "memory"); \
                       __builtin_amdgcn_s_barrier();  \
                       asm volatile("" ::: "memory"); } while (0)

__device__ __forceinline__ short f2bf(float f) {
    union { float f; unsigned u; } x; x.f = f;
    unsigned r = x.u + 0x7FFF + ((x.u >> 16) & 1);  // RNE
    return (short)(r >> 16);
}

// byte offset of chunk (row, cc) in a (bh,tensor) image; XOR-swizzled (G4)
__device__ __forceinline__ size_t swz(int row, int cc) {
    return ((size_t)(row >> 7) * TILEB) + ((row & 127) << 7) + ((cc ^ (row & 7)) << 4);
}

__device__ __forceinline__ void gload_lds16(const char* g, char* l) {
    __builtin_amdgcn_global_load_lds(
        (const __attribute__((address_space(1))) void*)g,
        (__attribute__((address_space(3))) void*)l, 16, 0, 0);
}
__device__ __forceinline__ void gload_lds4(const float* g, float* l) {
    __builtin_amdgcn_global_load_lds(
        (const __attribute__((address_space(1))) void*)g,
        (__attribute__((address_space(3))) void*)l, 4, 0, 0);
}

// ---------------------------------------------------------------------------
// Pre-pass: build bf16 swizzled image AND zero the accumulators (Z|CS|TK).
// ---------------------------------------------------------------------------
__global__ __launch_bounds__(512)
void mha_convert(const float* __restrict__ q, const float* __restrict__ k,
                 char* __restrict__ qk)
{
    const int gid = blockIdx.x * 512 + threadIdx.x;     // 2,097,152 threads
    if (gid < 2 * NZW + 4096)                           // zero Z + CS + TK
        ((int*)(qk + QKB))[gid] = 0;
    const int half = BH_ * N_ * 8;
    const bool isq = gid < half;
    const float* src = isq ? q : k;
    const float scl = isq ? QSCL : 1.0f;
    char* dst = qk + (isq ? 0 : (size_t)BH_ * BHB);
    const int id = isq ? gid : gid - half;
    const int bh  = id >> 14;
    const int row = (id >> 3) & 2047;
    const int cc  = id & 7;
    const float* p = src + ((size_t)bh * N_ + row) * D_ + cc * 8;
    float4 a = *(const float4*)p;
    float4 b = *(const float4*)(p + 4);
    bf16x8 o;
    o[0] = f2bf(a.x * scl); o[1] = f2bf(a.y * scl);
    o[2] = f2bf(a.z * scl); o[3] = f2bf(a.w * scl);
    o[4] = f2bf(b.x * scl); o[5] = f2bf(b.y * scl);
    o[6] = f2bf(b.z * scl); o[7] = f2bf(b.w * scl);
    *(bf16x8*)(dst + (size_t)bh * BHB + swz(row, cc)) = o;
}

// ---------------------------------------------------------------------------
// Pass 1: Z[n] += partial sum_m 2^(q'_n.k'_m)  (m split in 2 chunks, atomics);
// the 2nd-finishing wg of each (bh,rb) pair writes rinv = 1/Z for its rows.
// wg: 256 thr (4 waves x 32 rows), streams 16 x 64-row K' tiles, counted vmcnt.
// ---------------------------------------------------------------------------
__global__ __launch_bounds__(256, 6)
void mha_rowsum7(const char* __restrict__ qk, float* __restrict__ Z,
                 float* __restrict__ RI, int* __restrict__ TK)
{
    __shared__ __align__(16) char KT[2][TB64];
    __shared__ int go;

    const int t = threadIdx.x, w = t >> 6, l = t & 63;
    const int wid = (blockIdx.x & 7) * 256 + (blockIdx.x >> 3);  // XCD swizzle
    const int bh = wid >> 5, r = wid & 31, rb = r & 15, mc = r >> 4;

    const char* Qp = qk + (size_t)bh * BHB;
    const char* Kc = qk + (size_t)BH_ * BHB + (size_t)bh * BHB + (size_t)mc * NTC * TB64;

    bf16x8 af[2][2];
    #pragma unroll
    for (int rg = 0; rg < 2; ++rg)
        #pragma unroll
        for (int kh = 0; kh < 2; ++kh)
            af[rg][kh] = *(const bf16x8*)(Qp + swz(rb * 128 + w * 32 + rg * 16 + (l & 15),
                                                   kh * 4 + (l >> 4)));
    #pragma unroll
    for (int rg = 0; rg < 2; ++rg)
        #pragma unroll
        for (int kh = 0; kh < 2; ++kh)
            asm volatile("" :: "v"(af[rg][kh]));    // pin: pre-loop waitcnt

    const int lb0 = (l & 15) * 128 + (((l >> 4) ^ (l & 7)) << 4);
    const int lb1 = (l & 15) * 128 + (((4 + (l >> 4)) ^ (l & 7)) << 4);
    const int t16 = t * 16;

    float rs[2][4] = {};

    auto STAGE = [&](int ct, int buf) {             // 2 VMEM instrs per wave
        const char* src = Kc + (size_t)ct * TB64;
        gload_lds16(src + t16,        KT[buf] + t16);
        gload_lds16(src + 4096 + t16, KT[buf] + 4096 + t16);
    };
    auto COMPUTE = [&](const char* kt) {
        #pragma unroll
        for (int cj = 0; cj < 4; ++cj) {
            bf16x8 b0 = *(const bf16x8*)(kt + lb0 + cj * 2048);
            bf16x8 b1 = *(const bf16x8*)(kt + lb1 + cj * 2048);
            #pragma unroll
            for (int rg = 0; rg < 2; ++rg) {
                f32x4 c = {0.f, 0.f, 0.f, 0.f};
                c = __builtin_amdgcn_mfma_f32_16x16x32_bf16(af[rg][0], b0, c, 0, 0, 0);
                c = __builtin_amdgcn_mfma_f32_16x16x32_bf16(af[rg][1], b1, c, 0, 0, 0);
                rs[rg][0] += EXP2(c[0]);
                rs[rg][1] += EXP2(c[1]);
                rs[rg][2] += EXP2(c[2]);
                rs[rg][3] += EXP2(c[3]);
            }
        }
    };

    STAGE(0, 0);
    STAGE(1, 1);
    #pragma unroll 1
    for (int ct = 0; ct < NTC - 2; ++ct) {
        asm volatile("s_waitcnt vmcnt(2)" ::: "memory");
        BARRIER();
        COMPUTE(KT[ct & 1]);
        BARRIER();
        STAGE(ct + 2, ct & 1);
    }
    asm volatile("s_waitcnt vmcnt(2)" ::: "memory");
    BARRIER();
    COMPUTE(KT[(NTC - 2) & 1]);
    asm volatile("s_waitcnt vmcnt(0)" ::: "memory");
    BARRIER();
    COMPUTE(KT[(NTC - 1) & 1]);

    #pragma unroll
    for (int rg = 0; rg < 2; ++rg)
        #pragma unroll
        for (int i = 0; i < 4; ++i) {
            rs[rg][i] += __shfl_xor(rs[rg][i], 1);
            rs[rg][i] += __shfl_xor(rs[rg][i], 2);
            rs[rg][i] += __shfl_xor(rs[rg][i], 4);
            rs[rg][i] += __shfl_xor(rs[rg][i], 8);
        }
    if ((l & 15) == 0) {
        #pragma unroll
        for (int rg = 0; rg < 2; ++rg) {
            const int rbase = bh * N_ + rb * 128 + w * 32 + rg * 16 + (l >> 4) * 4;
            #pragma unroll
            for (int i = 0; i < 4; ++i)
                atomicAdd(&Z[rbase + i], rs[rg][i]);
        }
    }
    __syncthreads();                                 // all 4 waves' atomics drained
    if (t == 0) go = (atomicAdd(&TK[bh * 16 + rb], 1) == 1);
    __syncthreads();
    if (go) {                                        // 2nd wg: Z complete -> rinv
        __threadfence();
        if (t < 128) {
            const int idx = bh * N_ + rb * 128 + t;
            float z = __hip_atomic_load(&Z[idx], __ATOMIC_RELAXED, __HIP_MEMORY_SCOPE_AGENT);
            RI[idx] = 1.0f / z;
        }
    }
}

// ---------------------------------------------------------------------------
// Pass 2: CS[m] += partial sum_n 2^(q'_n.k'_m) * rinv[n]  (n split 2, atomics);
// 2nd-finishing wg of each (bh,cb) pair writes out = CS[m] * v[m,:].
// ---------------------------------------------------------------------------
__global__ __launch_bounds__(256, 6)
void mha_colsum7(const char* __restrict__ qk, const float* __restrict__ RI,
                 float* __restrict__ CS, int* __restrict__ TK,
                 const float* __restrict__ v, float* __restrict__ out)
{
    __shared__ __align__(16) char QT[2][TB64];
    __shared__ float rvw[2][4][64];
    __shared__ float lcs[128];
    __shared__ int go;

    const int t = threadIdx.x, w = t >> 6, l = t & 63;
    const int wid = (blockIdx.x & 7) * 256 + (blockIdx.x >> 3);
    const int bh = wid >> 5, r = wid & 31, cb = r & 15, nc = r >> 4;

    const char* Qc = qk + (size_t)bh * BHB + (size_t)nc * NTC * TB64;
    const char* Kp = qk + (size_t)BH_ * BHB + (size_t)bh * BHB;
    const float* Rc = RI + (size_t)bh * N_ + nc * (NTC * 64);

    bf16x8 kf[2][2];
    #pragma unroll
    for (int rg = 0; rg < 2; ++rg)
        #pragma unroll
        for (int kh = 0; kh < 2; ++kh)
            kf[rg][kh] = *(const bf16x8*)(Kp + swz(cb * 128 + w * 32 + rg * 16 + (l & 15),
                                                    kh * 4 + (l >> 4)));
    #pragma unroll
    for (int rg = 0; rg < 2; ++rg)
        #pragma unroll
        for (int kh = 0; kh < 2; ++kh)
            asm volatile("" :: "v"(kf[rg][kh]));

    const int lb0 = (l & 15) * 128 + (((l >> 4) ^ (l & 7)) << 4);
    const int lb1 = (l & 15) * 128 + (((4 + (l >> 4)) ^ (l & 7)) << 4);
    const int t16 = t * 16;

    float ca[2] = {0.f, 0.f};

    auto STAGE = [&](int rt, int buf) {             // 3 VMEM instrs per wave
        const char* src = Qc + (size_t)rt * TB64;
        gload_lds16(src + t16,        QT[buf] + t16);
        gload_lds16(src + 4096 + t16, QT[buf] + 4096 + t16);
        gload_lds4(Rc + rt * 64 + l, &rvw[buf][w][0] + l);
    };
    auto COMPUTE = [&](const char* qt, const float* rvb) {
        #pragma unroll
        for (int cj = 0; cj < 4; ++cj) {
            bf16x8 a0 = *(const bf16x8*)(qt + lb0 + cj * 2048);
            bf16x8 a1 = *(const bf16x8*)(qt + lb1 + cj * 2048);
            float4 r4 = *(const float4*)(rvb + cj * 16 + (l >> 4) * 4);
            #pragma unroll
            for (int rg = 0; rg < 2; ++rg) {
                f32x4 c = {0.f, 0.f, 0.f, 0.f};
                c = __builtin_amdgcn_mfma_f32_16x16x32_bf16(a0, kf[rg][0], c, 0, 0, 0);
                c = __builtin_amdgcn_mfma_f32_16x16x32_bf16(a1, kf[rg][1], c, 0, 0, 0);
                ca[rg] += EXP2(c[0]) * r4.x + EXP2(c[1]) * r4.y
                        + EXP2(c[2]) * r4.z + EXP2(c[3]) * r4.w;
            }
        }
    };

    STAGE(0, 0);
    STAGE(1, 1);
    #pragma unroll 1
    for (int rt = 0; rt < NTC - 2; ++rt) {
        asm volatile("s_waitcnt vmcnt(3)" ::: "memory");
        BARRIER();
        COMPUTE(QT[rt & 1], &rvw[rt & 1][w][0]);
        BARRIER();
        STAGE(rt + 2, rt & 1);
    }
    asm volatile("s_waitcnt vmcnt(3)" ::: "memory");
    BARRIER();
    COMPUTE(QT[(NTC - 2) & 1], &rvw[(NTC - 2) & 1][w][0]);
    asm volatile("s_waitcnt vmcnt(0)" ::: "memory");
    BARRIER();
    COMPUTE(QT[(NTC - 1) & 1], &rvw[(NTC - 1) & 1][w][0]);

    #pragma unroll
    for (int rg = 0; rg < 2; ++rg) {
        ca[rg] += __shfl_xor(ca[rg], 16);
        ca[rg] += __shfl_xor(ca[rg], 32);
    }
    if (l < 16) {
        atomicAdd(&CS[bh * N_ + cb * 128 + w * 32 + l],      ca[0]);
        atomicAdd(&CS[bh * N_ + cb * 128 + w * 32 + 16 + l], ca[1]);
    }
    __syncthreads();
    if (t == 0) go = (atomicAdd(&TK[1024 + bh * 16 + cb], 1) == 1);
    __syncthreads();
    if (go) {                                        // 2nd wg: CS complete -> out
        __threadfence();
        if (t < 128)
            lcs[t] = __hip_atomic_load(&CS[bh * N_ + cb * 128 + t],
                                       __ATOMIC_RELAXED, __HIP_MEMORY_SCOPE_AGENT);
        __syncthreads();
        const float4* Vg = (const float4*)(v + ((size_t)bh * N_ + cb * 128) * D_);
        float4* Og = (float4*)(out + ((size_t)bh * N_ + cb * 128) * D_);
        #pragma unroll
        for (int i = 0; i < 8; ++i) {
            int id = i * 256 + t;                    // 2048 float4 units
            float s = lcs[id >> 4];
            float4 vv = Vg[id];
            float4 o; o.x = vv.x * s; o.y = vv.y * s; o.z = vv.z * s; o.w = vv.w * s;
            Og[id] = o;
        }
    }
}

// ===========================================================================
// Fallback (R2 path) if ws_size is too small for the bf16 staging buffers.
// ===========================================================================
#define FTS 128
#define FNT 16

__device__ __forceinline__ bf16x8 cvt8(const float* p) {
    float4 a = *(const float4*)p;
    float4 b = *(const float4*)(p + 4);
    bf16x8 r;
    r[0] = f2bf(a.x); r[1] = f2bf(a.y); r[2] = f2bf(a.z); r[3] = f2bf(a.w);
    r[4] = f2bf(b.x); r[5] = f2bf(b.y); r[6] = f2bf(b.z); r[7] = f2bf(b.w);
    return r;
}
__device__ __forceinline__ void fstage(char* lds, const float* src, int t) {
    #pragma unroll
    for (int i = 0; i < 2; ++i) {
        int ch = i * 512 + t, r = ch >> 3, cc = ch & 7;
        bf16x8 v = cvt8(src + (size_t)r * D_ + cc * 8);
        *(bf16x8*)(lds + r * 128 + ((cc ^ (r & 7)) << 4)) = v;
    }
}
__device__ __forceinline__ bf16x8 fread(const char* lds, int row, int cc) {
    return *(const bf16x8*)(lds + row * 128 + ((cc ^ (row & 7)) << 4));
}

__global__ __launch_bounds__(512)
void mha_rowsum_fb(const float* __restrict__ q, const float* __restrict__ k,
                   float* __restrict__ rinv)
{
    __shared__ __align__(16) char KT[FTS * 128];
    const int t = threadIdx.x, w = t >> 6, l = t & 63;
    const int bh = blockIdx.x / FNT, rb = blockIdx.x % FNT;
    const float* Qg = q + (size_t)bh * N_ * D_;
    const float* Kg = k + (size_t)bh * N_ * D_;
    const int qrow = rb * FTS + w * 16 + (l & 15);
    bf16x8 af[2];
    #pragma unroll
    for (int kh = 0; kh < 2; ++kh)
        af[kh] = cvt8(Qg + (size_t)qrow * D_ + kh * 32 + (l >> 4) * 8);
    float rs[4] = {0.f, 0.f, 0.f, 0.f};
    for (int ct = 0; ct < FNT; ++ct) {
        __syncthreads();
        fstage(KT, Kg + (size_t)ct * FTS * D_, t);
        __syncthreads();
        #pragma unroll
        for (int cj = 0; cj < 8; ++cj) {
            const int krow = cj * 16 + (l & 15);
            f32x4 c = {0.f, 0.f, 0.f, 0.f};
            #pragma unroll
            for (int kh = 0; kh < 2; ++kh)
                c = __builtin_amdgcn_mfma_f32_16x16x32_bf16(af[kh], fread(KT, krow, kh * 4 + (l >> 4)), c, 0, 0, 0);
            rs[0] += __expf(c[0] * SCALE); rs[1] += __expf(c[1] * SCALE);
            rs[2] += __expf(c[2] * SCALE); rs[3] += __expf(c[3] * SCALE);
        }
    }
    #pragma unroll
    for (int i = 0; i < 4; ++i) {
        rs[i] += __shfl_xor(rs[i], 1); rs[i] += __shfl_xor(rs[i], 2);
        rs[i] += __shfl_xor(rs[i], 4); rs[i] += __shfl_xor(rs[i], 8);
    }
    if ((l & 15) == 0) {
        const int rbase = rb * FTS + w * 16 + (l >> 4) * 4;
        #pragma unroll
        for (int i = 0; i < 4; ++i)
            rinv[(size_t)bh * N_ + rbase + i] = 1.0f / rs[i];
    }
}

__global__ __launch_bounds__(512)
void mha_colsum_fb(const float* __restrict__ q, const float* __restrict__ k,
                   const float* __restrict__ v, const float* __restrict__ rinv,
                   float* __restrict__ out)
{
    __shared__ __align__(16) char QT[FTS * 128];
    __shared__ float rv[FTS];
    __shared__ float cs[FTS];
    const int t = threadIdx.x, w = t >> 6, l = t & 63;
    const int bh = blockIdx.x / FNT, cb = blockIdx.x % FNT;
    const float* Qg = q + (size_t)bh * N_ * D_;
    const float* Kg = k + (size_t)bh * N_ * D_;
    const float* Rg = rinv + (size_t)bh * N_;
    const int kcol = cb * FTS + w * 16 + (l & 15);
    bf16x8 kf[2];
    #pragma unroll
    for (int kh = 0; kh < 2; ++kh)
        kf[kh] = cvt8(Kg + (size_t)kcol * D_ + kh * 32 + (l >> 4) * 8);
    float ca = 0.f;
    for (int rt = 0; rt < FNT; ++rt) {
        __syncthreads();
        fstage(QT, Qg + (size_t)rt * FTS * D_, t);
        if (t < FTS) rv[t] = Rg[rt * FTS + t];
        __syncthreads();
        #pragma unroll
        for (int rj = 0; rj < 8; ++rj) {
            const int qr = rj * 16 + (l & 15);
            f32x4 c = {0.f, 0.f, 0.f, 0.f};
            #pragma unroll
            for (int kh = 0; kh < 2; ++kh)
                c = __builtin_amdgcn_mfma_f32_16x16x32_bf16(fread(QT, qr, kh * 4 + (l >> 4)), kf[kh], c, 0, 0, 0);
            float4 r4 = *(const float4*)&rv[rj * 16 + (l >> 4) * 4];
            ca += __expf(c[0] * SCALE) * r4.x + __expf(c[1] * SCALE) * r4.y
                + __expf(c[2] * SCALE) * r4.z + __expf(c[3] * SCALE) * r4.w;
        }
    }
    ca += __shfl_xor(ca, 16); ca += __shfl_xor(ca, 32);
    if (l < 16) cs[w * 16 + l] = ca;
    __syncthreads();
    const float4* Vg = (const float4*)(v + (size_t)bh * N_ * D_ + (size_t)cb * FTS * D_);
    float4* Og = (float4*)(out + (size_t)bh * N_ * D_ + (size_t)cb * FTS * D_);
    #pragma unroll
    for (int i = 0; i < 4; ++i) {
        int id = i * 512 + t;
        float s = cs[id >> 4];
        float4 vv = Vg[id];
        float4 o; o.x = vv.x * s; o.y = vv.y * s; o.z = vv.z * s; o.w = vv.w * s;
        Og[id] = o;
    }
}

// ---------------------------------------------------------------------------
extern "C" void kernel_launch(void* const* d_in, const int* in_sizes, int n_in,
                              void* d_out, int out_size, void* d_ws, size_t ws_size,
                              hipStream_t stream)
{
    const float* q = (const float*)d_in[0];
    const float* k = (const float*)d_in[1];
    const float* v = (const float*)d_in[2];
    float* out = (float*)d_out;

    // ws layout: qk image (32M) | Z (512K) | CS (512K) | TK (16K) | RI (512K)
    const size_t need = QKB + (size_t)NZW * 4 * 3 + 16384;

    if (ws_size >= need) {
        char*  qk = (char*)d_ws;
        float* Z  = (float*)(qk + QKB);
        float* CS = Z + NZW;
        int*   TK = (int*)(CS + NZW);
        float* RI = (float*)((char*)TK + 16384);
        mha_convert<<<dim3(2 * BH_ * N_ * 8 / 512), dim3(512), 0, stream>>>(q, k, qk);
        mha_rowsum7<<<dim3(2048), dim3(256), 0, stream>>>(qk, Z, RI, TK);
        mha_colsum7<<<dim3(2048), dim3(256), 0, stream>>>(qk, RI, CS, TK, v, out);
    } else {
        float* rinv = (float*)d_ws;
        mha_rowsum_fb<<<dim3(BH_ * FNT), dim3(512), 0, stream>>>(q, k, rinv);
        mha_colsum_fb<<<dim3(BH_ * FNT), dim3(512), 0, stream>>>(q, k, v, rinv, out);
    }
}

// Round 13
// 123.199 us; speedup vs baseline: 2.2744x; 2.2744x over previous
//
#include <hip/hip_runtime.h>
#include <cstdint>
#include <cstddef>

// [B,H,N,Dh] = [4,16,2048,64]; out[b,h,m,d] = (sum_n softmax(QK^T)[n,m]) * v[b,h,m,d]
#define B_    4
#define H_    16
#define N_    2048
#define D_    64
#define BH_   (B_*H_)
#define SCALE 0.125f
#define QSCL  0.18033688011f      // SCALE * log2(e)

#define PNL   128                 // fixed panel (rows pass1 / cols pass2) per wg
#define NPN   (N_/PNL)            // 16
#define TILEB 16384               // 128 rows of bf16[64] = 16 KB
#define BHB   (16*TILEB)          // 256 KB per (bh, tensor)
#define QKB   ((size_t)2*BH_*BHB) // 32 MB image
#define NG    128                 // fragment-groups per image (2 KB each)

typedef __attribute__((ext_vector_type(8))) short bf16x8;
typedef __attribute__((ext_vector_type(4))) float f32x4;

#if __has_builtin(__builtin_amdgcn_exp2f)
#define EXP2(x) __builtin_amdgcn_exp2f(x)
#else
#define EXP2(x) exp2f(x)
#endif

__device__ __forceinline__ short f2bf(float f) {
    union { float f; unsigned u; } x; x.f = f;
    unsigned r = x.u + 0x7FFF + ((x.u >> 16) & 1);  // RNE
    return (short)(r >> 16);
}

// Fragment-major byte offset of chunk (row, cc) in a (bh,tensor) image:
// tile = row>>7; group g=(row>>4)&7 (2 KB); frag f=cc>>2 (1 KB);
// lane l=(cc&3)*16+(row&15) at l*16. Streamed reads are base + l*16, and the
// image is 128 sequential 2 KB fragment-groups -> fully coalesced, no LDS.
__device__ __forceinline__ size_t fmaj(int row, int cc) {
    return ((size_t)(row >> 7) * TILEB) + (((row >> 4) & 7) << 11)
         + ((cc >> 2) << 10) + ((cc & 3) << 8) + ((row & 15) << 4);
}

// ---------------------------------------------------------------------------
// Pre-pass: qk[] = [ Q' (bf16, x QSCL) | K' (bf16) ], fragment-major layout
// ---------------------------------------------------------------------------
__global__ __launch_bounds__(512)
void mha_convert(const float* __restrict__ q, const float* __restrict__ k,
                 char* __restrict__ qk)
{
    const int gid = blockIdx.x * 512 + threadIdx.x;     // 2*64*16384 chunks
    const int half = BH_ * N_ * 8;
    const bool isq = gid < half;
    const float* src = isq ? q : k;
    const float scl = isq ? QSCL : 1.0f;
    char* dst = qk + (isq ? 0 : (size_t)BH_ * BHB);
    const int id = isq ? gid : gid - half;
    const int bh  = id >> 14;
    const int row = (id >> 3) & 2047;
    const int cc  = id & 7;
    const float* p = src + ((size_t)bh * N_ + row) * D_ + cc * 8;
    float4 a = *(const float4*)p;
    float4 b = *(const float4*)(p + 4);
    bf16x8 o;
    o[0] = f2bf(a.x * scl); o[1] = f2bf(a.y * scl);
    o[2] = f2bf(a.z * scl); o[3] = f2bf(a.w * scl);
    o[4] = f2bf(b.x * scl); o[5] = f2bf(b.y * scl);
    o[6] = f2bf(b.z * scl); o[7] = f2bf(b.w * scl);
    *(bf16x8*)(dst + (size_t)bh * BHB + fmaj(row, cc)) = o;
}

// ---------------------------------------------------------------------------
// Pass 1: rinv[bh,n] = 1 / sum_m 2^(q'_n . k'_m)
// wg = (bh, 128-row panel); 4 waves x 32 rows (rg=2). K' streamed straight
// from L2 (fragment-major, coalesced), depth-1 register prefetch, NO barriers.
// ---------------------------------------------------------------------------
__global__ __launch_bounds__(256)
void mha_rowsum8(const char* __restrict__ qk, float* __restrict__ rinv)
{
    const int t = threadIdx.x, w = t >> 6, l = t & 63;
    const int wid = (blockIdx.x & 7) * 128 + (blockIdx.x >> 3);  // XCD swizzle
    const int bh = wid >> 4, rb = wid & 15;

    const char* Qp = qk + (size_t)bh * BHB;
    const char* Kp = qk + (size_t)BH_ * BHB + (size_t)bh * BHB;

    // Fixed A frags: rows rb*128 + w*32 + rg*16 + (l&15)
    bf16x8 af0_0, af0_1, af1_0, af1_1;
    {
        const char* g0 = Qp + rb * TILEB + (w * 2 + 0) * 2048;
        const char* g1 = Qp + rb * TILEB + (w * 2 + 1) * 2048;
        af0_0 = *(const bf16x8*)(g0 + l * 16);
        af0_1 = *(const bf16x8*)(g0 + 1024 + l * 16);
        af1_0 = *(const bf16x8*)(g1 + l * 16);
        af1_1 = *(const bf16x8*)(g1 + 1024 + l * 16);
    }

    float rs[2][4] = {};
    const char* pl = Kp + l * 16;

    bf16x8 c0 = *(const bf16x8*)(pl);
    bf16x8 c1 = *(const bf16x8*)(pl + 1024);

#define RS_COMP(B0, B1)                                                      \
    do {                                                                     \
        f32x4 ch0 = {0.f, 0.f, 0.f, 0.f};                                    \
        ch0 = __builtin_amdgcn_mfma_f32_16x16x32_bf16(af0_0, (B0), ch0, 0, 0, 0); \
        ch0 = __builtin_amdgcn_mfma_f32_16x16x32_bf16(af0_1, (B1), ch0, 0, 0, 0); \
        f32x4 ch1 = {0.f, 0.f, 0.f, 0.f};                                    \
        ch1 = __builtin_amdgcn_mfma_f32_16x16x32_bf16(af1_0, (B0), ch1, 0, 0, 0); \
        ch1 = __builtin_amdgcn_mfma_f32_16x16x32_bf16(af1_1, (B1), ch1, 0, 0, 0); \
        rs[0][0] += EXP2(ch0[0]); rs[0][1] += EXP2(ch0[1]);                  \
        rs[0][2] += EXP2(ch0[2]); rs[0][3] += EXP2(ch0[3]);                  \
        rs[1][0] += EXP2(ch1[0]); rs[1][1] += EXP2(ch1[1]);                  \
        rs[1][2] += EXP2(ch1[2]); rs[1][3] += EXP2(ch1[3]);                  \
    } while (0)

    #pragma unroll 2
    for (int gi = 0; gi < NG - 1; ++gi) {
        bf16x8 n0 = *(const bf16x8*)(pl + (size_t)(gi + 1) * 2048);
        bf16x8 n1 = *(const bf16x8*)(pl + (size_t)(gi + 1) * 2048 + 1024);
        RS_COMP(c0, c1);
        c0 = n0; c1 = n1;
    }
    RS_COMP(c0, c1);
#undef RS_COMP

    // Reduce across the 16 col-lanes; S-row = rg*16 + (l>>4)*4 + i
    #pragma unroll
    for (int rg = 0; rg < 2; ++rg)
        #pragma unroll
        for (int i = 0; i < 4; ++i) {
            rs[rg][i] += __shfl_xor(rs[rg][i], 1);
            rs[rg][i] += __shfl_xor(rs[rg][i], 2);
            rs[rg][i] += __shfl_xor(rs[rg][i], 4);
            rs[rg][i] += __shfl_xor(rs[rg][i], 8);
        }
    if ((l & 15) == 0) {
        #pragma unroll
        for (int rg = 0; rg < 2; ++rg) {
            const int rbase = bh * N_ + rb * PNL + w * 32 + rg * 16 + (l >> 4) * 4;
            #pragma unroll
            for (int i = 0; i < 4; ++i)
                rinv[rbase + i] = 1.0f / rs[rg][i];
        }
    }
}

// ---------------------------------------------------------------------------
// Pass 2: colsum[m] = sum_n 2^(q'_n . k'_m) * rinv[n]; out = colsum[m]*v[m,:]
// wg = (bh, 128-col panel); Q' + rinv streamed from L2, register prefetch,
// no barriers (one __syncthreads for the epilogue only).
// ---------------------------------------------------------------------------
__global__ __launch_bounds__(256)
void mha_colsum8(const char* __restrict__ qk, const float* __restrict__ rinv,
                 const float* __restrict__ v, float* __restrict__ out)
{
    __shared__ float cs[PNL];

    const int t = threadIdx.x, w = t >> 6, l = t & 63;
    const int wid = (blockIdx.x & 7) * 128 + (blockIdx.x >> 3);
    const int bh = wid >> 4, cb = wid & 15;

    const char* Qp = qk + (size_t)bh * BHB;
    const char* Kp = qk + (size_t)BH_ * BHB + (size_t)bh * BHB;
    const float* Rg = rinv + (size_t)bh * N_;

    // Fixed B frags: cols cb*128 + w*32 + rg*16 + (l&15)
    bf16x8 kf0_0, kf0_1, kf1_0, kf1_1;
    {
        const char* g0 = Kp + cb * TILEB + (w * 2 + 0) * 2048;
        const char* g1 = Kp + cb * TILEB + (w * 2 + 1) * 2048;
        kf0_0 = *(const bf16x8*)(g0 + l * 16);
        kf0_1 = *(const bf16x8*)(g0 + 1024 + l * 16);
        kf1_0 = *(const bf16x8*)(g1 + l * 16);
        kf1_1 = *(const bf16x8*)(g1 + 1024 + l * 16);
    }

    float ca0 = 0.f, ca1 = 0.f;
    const char* pl = Qp + l * 16;
    const float* Rl = Rg + (l >> 4) * 4;

    bf16x8 c0 = *(const bf16x8*)(pl);
    bf16x8 c1 = *(const bf16x8*)(pl + 1024);
    float4 rc = *(const float4*)(Rl);

#define CS_COMP(A0, A1, R4)                                                  \
    do {                                                                     \
        f32x4 ch0 = {0.f, 0.f, 0.f, 0.f};                                    \
        ch0 = __builtin_amdgcn_mfma_f32_16x16x32_bf16((A0), kf0_0, ch0, 0, 0, 0); \
        ch0 = __builtin_amdgcn_mfma_f32_16x16x32_bf16((A1), kf0_1, ch0, 0, 0, 0); \
        f32x4 ch1 = {0.f, 0.f, 0.f, 0.f};                                    \
        ch1 = __builtin_amdgcn_mfma_f32_16x16x32_bf16((A0), kf1_0, ch1, 0, 0, 0); \
        ch1 = __builtin_amdgcn_mfma_f32_16x16x32_bf16((A1), kf1_1, ch1, 0, 0, 0); \
        ca0 += EXP2(ch0[0]) * (R4).x + EXP2(ch0[1]) * (R4).y                 \
             + EXP2(ch0[2]) * (R4).z + EXP2(ch0[3]) * (R4).w;                \
        ca1 += EXP2(ch1[0]) * (R4).x + EXP2(ch1[1]) * (R4).y                 \
             + EXP2(ch1[2]) * (R4).z + EXP2(ch1[3]) * (R4).w;                \
    } while (0)

    #pragma unroll 2
    for (int gi = 0; gi < NG - 1; ++gi) {
        bf16x8 n0 = *(const bf16x8*)(pl + (size_t)(gi + 1) * 2048);
        bf16x8 n1 = *(const bf16x8*)(pl + (size_t)(gi + 1) * 2048 + 1024);
        float4 rn = *(const float4*)(Rl + (gi + 1) * 16);
        CS_COMP(c0, c1, rc);
        c0 = n0; c1 = n1; rc = rn;
    }
    CS_COMP(c0, c1, rc);
#undef CS_COMP

    // Butterfly over the 4 row-groups -> lanes 0..15 hold colsum of col rg*16+l
    ca0 += __shfl_xor(ca0, 16); ca0 += __shfl_xor(ca0, 32);
    ca1 += __shfl_xor(ca1, 16); ca1 += __shfl_xor(ca1, 32);
    if (l < 16) { cs[w * 32 + l] = ca0; cs[w * 32 + 16 + l] = ca1; }
    __syncthreads();

    // out[m][d] = colsum[m] * v[m][d]  (128 rows x 64 d, float4-vectorized)
    const float4* Vg = (const float4*)(v + ((size_t)bh * N_ + cb * PNL) * D_);
    float4* Og = (float4*)(out + ((size_t)bh * N_ + cb * PNL) * D_);
    #pragma unroll
    for (int i = 0; i < 8; ++i) {
        int id = i * 256 + t;                // 2048 float4 units
        float s = cs[id >> 4];
        float4 vv = Vg[id];
        float4 o; o.x = vv.x * s; o.y = vv.y * s; o.z = vv.z * s; o.w = vv.w * s;
        Og[id] = o;
    }
}

// ===========================================================================
// Fallback (R2 path) if ws_size is too small for the bf16 staging buffers.
// ===========================================================================
#define FTS 128
#define FNT 16

__device__ __forceinline__ bf16x8 cvt8(const float* p) {
    float4 a = *(const float4*)p;
    float4 b = *(const float4*)(p + 4);
    bf16x8 r;
    r[0] = f2bf(a.x); r[1] = f2bf(a.y); r[2] = f2bf(a.z); r[3] = f2bf(a.w);
    r[4] = f2bf(b.x); r[5] = f2bf(b.y); r[6] = f2bf(b.z); r[7] = f2bf(b.w);
    return r;
}
__device__ __forceinline__ void fstage(char* lds, const float* src, int t) {
    #pragma unroll
    for (int i = 0; i < 2; ++i) {
        int ch = i * 512 + t, r = ch >> 3, cc = ch & 7;
        bf16x8 v = cvt8(src + (size_t)r * D_ + cc * 8);
        *(bf16x8*)(lds + r * 128 + ((cc ^ (r & 7)) << 4)) = v;
    }
}
__device__ __forceinline__ bf16x8 fread(const char* lds, int row, int cc) {
    return *(const bf16x8*)(lds + row * 128 + ((cc ^ (row & 7)) << 4));
}

__global__ __launch_bounds__(512)
void mha_rowsum_fb(const float* __restrict__ q, const float* __restrict__ k,
                   float* __restrict__ rinv)
{
    __shared__ __align__(16) char KT[FTS * 128];
    const int t = threadIdx.x, w = t >> 6, l = t & 63;
    const int bh = blockIdx.x / FNT, rb = blockIdx.x % FNT;
    const float* Qg = q + (size_t)bh * N_ * D_;
    const float* Kg = k + (size_t)bh * N_ * D_;
    const int qrow = rb * FTS + w * 16 + (l & 15);
    bf16x8 af[2];
    #pragma unroll
    for (int kh = 0; kh < 2; ++kh)
        af[kh] = cvt8(Qg + (size_t)qrow * D_ + kh * 32 + (l >> 4) * 8);
    float rs[4] = {0.f, 0.f, 0.f, 0.f};
    for (int ct = 0; ct < FNT; ++ct) {
        __syncthreads();
        fstage(KT, Kg + (size_t)ct * FTS * D_, t);
        __syncthreads();
        #pragma unroll
        for (int cj = 0; cj < 8; ++cj) {
            const int krow = cj * 16 + (l & 15);
            f32x4 c = {0.f, 0.f, 0.f, 0.f};
            #pragma unroll
            for (int kh = 0; kh < 2; ++kh)
                c = __builtin_amdgcn_mfma_f32_16x16x32_bf16(af[kh], fread(KT, krow, kh * 4 + (l >> 4)), c, 0, 0, 0);
            rs[0] += __expf(c[0] * SCALE); rs[1] += __expf(c[1] * SCALE);
            rs[2] += __expf(c[2] * SCALE); rs[3] += __expf(c[3] * SCALE);
        }
    }
    #pragma unroll
    for (int i = 0; i < 4; ++i) {
        rs[i] += __shfl_xor(rs[i], 1); rs[i] += __shfl_xor(rs[i], 2);
        rs[i] += __shfl_xor(rs[i], 4); rs[i] += __shfl_xor(rs[i], 8);
    }
    if ((l & 15) == 0) {
        const int rbase = rb * FTS + w * 16 + (l >> 4) * 4;
        #pragma unroll
        for (int i = 0; i < 4; ++i)
            rinv[(size_t)bh * N_ + rbase + i] = 1.0f / rs[i];
    }
}

__global__ __launch_bounds__(512)
void mha_colsum_fb(const float* __restrict__ q, const float* __restrict__ k,
                   const float* __restrict__ v, const float* __restrict__ rinv,
                   float* __restrict__ out)
{
    __shared__ __align__(16) char QT[FTS * 128];
    __shared__ float rv[FTS];
    __shared__ float cs2[FTS];
    const int t = threadIdx.x, w = t >> 6, l = t & 63;
    const int bh = blockIdx.x / FNT, cb = blockIdx.x % FNT;
    const float* Qg = q + (size_t)bh * N_ * D_;
    const float* Kg = k + (size_t)bh * N_ * D_;
    const float* Rg = rinv + (size_t)bh * N_;
    const int kcol = cb * FTS + w * 16 + (l & 15);
    bf16x8 kf[2];
    #pragma unroll
    for (int kh = 0; kh < 2; ++kh)
        kf[kh] = cvt8(Kg + (size_t)kcol * D_ + kh * 32 + (l >> 4) * 8);
    float ca = 0.f;
    for (int rt = 0; rt < FNT; ++rt) {
        __syncthreads();
        fstage(QT, Qg + (size_t)rt * FTS * D_, t);
        if (t < FTS) rv[t] = Rg[rt * FTS + t];
        __syncthreads();
        #pragma unroll
        for (int rj = 0; rj < 8; ++rj) {
            const int qr = rj * 16 + (l & 15);
            f32x4 c = {0.f, 0.f, 0.f, 0.f};
            #pragma unroll
            for (int kh = 0; kh < 2; ++kh)
                c = __builtin_amdgcn_mfma_f32_16x16x32_bf16(fread(QT, qr, kh * 4 + (l >> 4)), kf[kh], c, 0, 0, 0);
            float4 r4 = *(const float4*)&rv[rj * 16 + (l >> 4) * 4];
            ca += __expf(c[0] * SCALE) * r4.x + __expf(c[1] * SCALE) * r4.y
                + __expf(c[2] * SCALE) * r4.z + __expf(c[3] * SCALE) * r4.w;
        }
    }
    ca += __shfl_xor(ca, 16); ca += __shfl_xor(ca, 32);
    if (l < 16) cs2[w * 16 + l] = ca;
    __syncthreads();
    const float4* Vg = (const float4*)(v + (size_t)bh * N_ * D_ + (size_t)cb * FTS * D_);
    float4* Og = (float4*)(out + (size_t)bh * N_ * D_ + (size_t)cb * FTS * D_);
    #pragma unroll
    for (int i = 0; i < 4; ++i) {
        int id = i * 512 + t;
        float s = cs2[id >> 4];
        float4 vv = Vg[id];
        float4 o; o.x = vv.x * s; o.y = vv.y * s; o.z = vv.z * s; o.w = vv.w * s;
        Og[id] = o;
    }
}

// ---------------------------------------------------------------------------
extern "C" void kernel_launch(void* const* d_in, const int* in_sizes, int n_in,
                              void* d_out, int out_size, void* d_ws, size_t ws_size,
                              hipStream_t stream)
{
    const float* q = (const float*)d_in[0];
    const float* k = (const float*)d_in[1];
    const float* v = (const float*)d_in[2];
    float* out = (float*)d_out;

    const size_t need = QKB + (size_t)BH_ * N_ * 4;        // image + rinv

    if (ws_size >= need) {
        char*  qk   = (char*)d_ws;
        float* rinv = (float*)(qk + QKB);
        mha_convert<<<dim3(2 * BH_ * N_ * 8 / 512), dim3(512), 0, stream>>>(q, k, qk);
        mha_rowsum8<<<dim3(BH_ * NPN), dim3(256), 0, stream>>>(qk, rinv);
        mha_colsum8<<<dim3(BH_ * NPN), dim3(256), 0, stream>>>(qk, rinv, v, out);
    } else {
        float* rinv = (float*)d_ws;
        mha_rowsum_fb<<<dim3(BH_ * FNT), dim3(512), 0, stream>>>(q, k, rinv);
        mha_colsum_fb<<<dim3(BH_ * FNT), dim3(512), 0, stream>>>(q, k, v, rinv, out);
    }
}

// Round 14
// 113.867 us; speedup vs baseline: 2.4608x; 1.0820x over previous
//
#include <hip/hip_runtime.h>
#include <cstdint>
#include <cstddef>

// [B,H,N,Dh] = [4,16,2048,64]; out[b,h,m,d] = (sum_n softmax(QK^T)[n,m]) * v[b,h,m,d]
#define B_    4
#define H_    16
#define N_    2048
#define D_    64
#define BH_   (B_*H_)
#define SCALE 0.125f
#define QSCL  0.18033688011f      // SCALE * log2(e)

#define PNL   128                 // fixed panel (rows pass1 / cols pass2) per wg
#define NPN   (N_/PNL)            // 16
#define TILEB 16384               // 128 rows of bf16[64] = 16 KB
#define BHB   (16*TILEB)          // 256 KB per (bh, tensor)
#define QKB   ((size_t)2*BH_*BHB) // 32 MB image
#define NG    128                 // fragment-groups per image (2 KB each)

typedef __attribute__((ext_vector_type(8))) short bf16x8;
typedef __attribute__((ext_vector_type(4))) float f32x4;

#if __has_builtin(__builtin_amdgcn_exp2f)
#define EXP2(x) __builtin_amdgcn_exp2f(x)
#else
#define EXP2(x) exp2f(x)
#endif

__device__ __forceinline__ short f2bf(float f) {
    union { float f; unsigned u; } x; x.f = f;
    unsigned r = x.u + 0x7FFF + ((x.u >> 16) & 1);  // RNE
    return (short)(r >> 16);
}

// Fragment-major byte offset of chunk (row, cc) in a (bh,tensor) image:
// tile = row>>7; group g=(row>>4)&7 (2 KB); frag f=cc>>2 (1 KB);
// lane l=(cc&3)*16+(row&15) at l*16. Streamed reads are base + l*16; image is
// 128 sequential 2 KB fragment-groups -> fully coalesced, no LDS needed.
__device__ __forceinline__ size_t fmaj(int row, int cc) {
    return ((size_t)(row >> 7) * TILEB) + (((row >> 4) & 7) << 11)
         + ((cc >> 2) << 10) + ((cc & 3) << 8) + ((row & 15) << 4);
}

// ---------------------------------------------------------------------------
// Pre-pass: qk[] = [ Q' (bf16, x QSCL) | K' (bf16) ], fragment-major layout
// ---------------------------------------------------------------------------
__global__ __launch_bounds__(512)
void mha_convert(const float* __restrict__ q, const float* __restrict__ k,
                 char* __restrict__ qk)
{
    const int gid = blockIdx.x * 512 + threadIdx.x;     // 2*64*16384 chunks
    const int half = BH_ * N_ * 8;
    const bool isq = gid < half;
    const float* src = isq ? q : k;
    const float scl = isq ? QSCL : 1.0f;
    char* dst = qk + (isq ? 0 : (size_t)BH_ * BHB);
    const int id = isq ? gid : gid - half;
    const int bh  = id >> 14;
    const int row = (id >> 3) & 2047;
    const int cc  = id & 7;
    const float* p = src + ((size_t)bh * N_ + row) * D_ + cc * 8;
    float4 a = *(const float4*)p;
    float4 b = *(const float4*)(p + 4);
    bf16x8 o;
    o[0] = f2bf(a.x * scl); o[1] = f2bf(a.y * scl);
    o[2] = f2bf(a.z * scl); o[3] = f2bf(a.w * scl);
    o[4] = f2bf(b.x * scl); o[5] = f2bf(b.y * scl);
    o[6] = f2bf(b.z * scl); o[7] = f2bf(b.w * scl);
    *(bf16x8*)(dst + (size_t)bh * BHB + fmaj(row, cc)) = o;
}

// ---------------------------------------------------------------------------
// Pass 1: rinv[bh,n] = 1 / sum_m 2^(q'_n . k'_m)
// wg = (bh, 128-row panel); 4 waves x 32 rows (rg=2). K' streamed from L2
// (fragment-major, coalesced), explicit DEPTH-4 register pipeline, no barriers.
// __launch_bounds__(256,4): VGPR cap 128 (room for pipeline, no spill),
// guaranteed 4 blocks/CU = 16 waves/CU.
// ---------------------------------------------------------------------------
__global__ __launch_bounds__(256, 4)
void mha_rowsum9(const char* __restrict__ qk, float* __restrict__ rinv)
{
    const int t = threadIdx.x, w = t >> 6, l = t & 63;
    const int wid = (blockIdx.x & 7) * 128 + (blockIdx.x >> 3);  // XCD swizzle
    const int bh = wid >> 4, rb = wid & 15;

    const char* Qp = qk + (size_t)bh * BHB;
    const char* Kp = qk + (size_t)BH_ * BHB + (size_t)bh * BHB;

    // Fixed A frags: rows rb*128 + w*32 + rg*16 + (l&15)
    bf16x8 af0_0, af0_1, af1_0, af1_1;
    {
        const char* g0 = Qp + rb * TILEB + (w * 2 + 0) * 2048;
        const char* g1 = Qp + rb * TILEB + (w * 2 + 1) * 2048;
        af0_0 = *(const bf16x8*)(g0 + l * 16);
        af0_1 = *(const bf16x8*)(g0 + 1024 + l * 16);
        af1_0 = *(const bf16x8*)(g1 + l * 16);
        af1_1 = *(const bf16x8*)(g1 + 1024 + l * 16);
    }

    float rs[2][4] = {};
    const char* pl = Kp + l * 16;

#define RS_COMP(B0, B1)                                                      \
    do {                                                                     \
        f32x4 ch0 = {0.f, 0.f, 0.f, 0.f};                                    \
        ch0 = __builtin_amdgcn_mfma_f32_16x16x32_bf16(af0_0, (B0), ch0, 0, 0, 0); \
        ch0 = __builtin_amdgcn_mfma_f32_16x16x32_bf16(af0_1, (B1), ch0, 0, 0, 0); \
        f32x4 ch1 = {0.f, 0.f, 0.f, 0.f};                                    \
        ch1 = __builtin_amdgcn_mfma_f32_16x16x32_bf16(af1_0, (B0), ch1, 0, 0, 0); \
        ch1 = __builtin_amdgcn_mfma_f32_16x16x32_bf16(af1_1, (B1), ch1, 0, 0, 0); \
        rs[0][0] += EXP2(ch0[0]); rs[0][1] += EXP2(ch0[1]);                  \
        rs[0][2] += EXP2(ch0[2]); rs[0][3] += EXP2(ch0[3]);                  \
        rs[1][0] += EXP2(ch1[0]); rs[1][1] += EXP2(ch1[1]);                  \
        rs[1][2] += EXP2(ch1[2]); rs[1][3] += EXP2(ch1[3]);                  \
    } while (0)

#define RS_LOAD(PA, PB, G) \
    do { PA = *(const bf16x8*)(pl + (size_t)(G) * 2048); \
         PB = *(const bf16x8*)(pl + (size_t)(G) * 2048 + 1024); } while (0)

    // Depth-4 rotating pipeline, statically named (rule #20)
    bf16x8 p0a, p0b, p1a, p1b, p2a, p2b, p3a, p3b;
    RS_LOAD(p0a, p0b, 0);
    RS_LOAD(p1a, p1b, 1);
    RS_LOAD(p2a, p2b, 2);
    RS_LOAD(p3a, p3b, 3);

    #pragma unroll 1
    for (int g = 0; g < NG - 4; g += 4) {
        RS_COMP(p0a, p0b); RS_LOAD(p0a, p0b, g + 4);
        RS_COMP(p1a, p1b); RS_LOAD(p1a, p1b, g + 5);
        RS_COMP(p2a, p2b); RS_LOAD(p2a, p2b, g + 6);
        RS_COMP(p3a, p3b); RS_LOAD(p3a, p3b, g + 7);
    }
    RS_COMP(p0a, p0b);
    RS_COMP(p1a, p1b);
    RS_COMP(p2a, p2b);
    RS_COMP(p3a, p3b);
#undef RS_COMP
#undef RS_LOAD

    // Reduce across the 16 col-lanes; S-row = rg*16 + (l>>4)*4 + i
    #pragma unroll
    for (int rg = 0; rg < 2; ++rg)
        #pragma unroll
        for (int i = 0; i < 4; ++i) {
            rs[rg][i] += __shfl_xor(rs[rg][i], 1);
            rs[rg][i] += __shfl_xor(rs[rg][i], 2);
            rs[rg][i] += __shfl_xor(rs[rg][i], 4);
            rs[rg][i] += __shfl_xor(rs[rg][i], 8);
        }
    if ((l & 15) == 0) {
        #pragma unroll
        for (int rg = 0; rg < 2; ++rg) {
            const int rbase = bh * N_ + rb * PNL + w * 32 + rg * 16 + (l >> 4) * 4;
            #pragma unroll
            for (int i = 0; i < 4; ++i)
                rinv[rbase + i] = 1.0f / rs[rg][i];
        }
    }
}

// ---------------------------------------------------------------------------
// Pass 2: colsum[m] = sum_n 2^(q'_n . k'_m) * rinv[n]; out = colsum[m]*v[m,:]
// wg = (bh, 128-col panel); Q' + rinv streamed from L2, depth-4 pipeline.
// ---------------------------------------------------------------------------
__global__ __launch_bounds__(256, 4)
void mha_colsum9(const char* __restrict__ qk, const float* __restrict__ rinv,
                 const float* __restrict__ v, float* __restrict__ out)
{
    __shared__ float cs[PNL];

    const int t = threadIdx.x, w = t >> 6, l = t & 63;
    const int wid = (blockIdx.x & 7) * 128 + (blockIdx.x >> 3);
    const int bh = wid >> 4, cb = wid & 15;

    const char* Qp = qk + (size_t)bh * BHB;
    const char* Kp = qk + (size_t)BH_ * BHB + (size_t)bh * BHB;
    const float* Rg = rinv + (size_t)bh * N_;

    // Fixed B frags: cols cb*128 + w*32 + rg*16 + (l&15)
    bf16x8 kf0_0, kf0_1, kf1_0, kf1_1;
    {
        const char* g0 = Kp + cb * TILEB + (w * 2 + 0) * 2048;
        const char* g1 = Kp + cb * TILEB + (w * 2 + 1) * 2048;
        kf0_0 = *(const bf16x8*)(g0 + l * 16);
        kf0_1 = *(const bf16x8*)(g0 + 1024 + l * 16);
        kf1_0 = *(const bf16x8*)(g1 + l * 16);
        kf1_1 = *(const bf16x8*)(g1 + 1024 + l * 16);
    }

    float ca0 = 0.f, ca1 = 0.f;
    const char* pl = Qp + l * 16;
    const float* Rl = Rg + (l >> 4) * 4;

#define CS_COMP(A0, A1, R4)                                                  \
    do {                                                                     \
        f32x4 ch0 = {0.f, 0.f, 0.f, 0.f};                                    \
        ch0 = __builtin_amdgcn_mfma_f32_16x16x32_bf16((A0), kf0_0, ch0, 0, 0, 0); \
        ch0 = __builtin_amdgcn_mfma_f32_16x16x32_bf16((A1), kf0_1, ch0, 0, 0, 0); \
        f32x4 ch1 = {0.f, 0.f, 0.f, 0.f};                                    \
        ch1 = __builtin_amdgcn_mfma_f32_16x16x32_bf16((A0), kf1_0, ch1, 0, 0, 0); \
        ch1 = __builtin_amdgcn_mfma_f32_16x16x32_bf16((A1), kf1_1, ch1, 0, 0, 0); \
        ca0 += EXP2(ch0[0]) * (R4).x + EXP2(ch0[1]) * (R4).y                 \
             + EXP2(ch0[2]) * (R4).z + EXP2(ch0[3]) * (R4).w;                \
        ca1 += EXP2(ch1[0]) * (R4).x + EXP2(ch1[1]) * (R4).y                 \
             + EXP2(ch1[2]) * (R4).z + EXP2(ch1[3]) * (R4).w;                \
    } while (0)

#define CS_LOAD(PA, PB, PR, G) \
    do { PA = *(const bf16x8*)(pl + (size_t)(G) * 2048);          \
         PB = *(const bf16x8*)(pl + (size_t)(G) * 2048 + 1024);   \
         PR = *(const float4*)(Rl + (G) * 16); } while (0)

    bf16x8 p0a, p0b, p1a, p1b, p2a, p2b, p3a, p3b;
    float4 r0, r1, r2, r3;
    CS_LOAD(p0a, p0b, r0, 0);
    CS_LOAD(p1a, p1b, r1, 1);
    CS_LOAD(p2a, p2b, r2, 2);
    CS_LOAD(p3a, p3b, r3, 3);

    #pragma unroll 1
    for (int g = 0; g < NG - 4; g += 4) {
        CS_COMP(p0a, p0b, r0); CS_LOAD(p0a, p0b, r0, g + 4);
        CS_COMP(p1a, p1b, r1); CS_LOAD(p1a, p1b, r1, g + 5);
        CS_COMP(p2a, p2b, r2); CS_LOAD(p2a, p2b, r2, g + 6);
        CS_COMP(p3a, p3b, r3); CS_LOAD(p3a, p3b, r3, g + 7);
    }
    CS_COMP(p0a, p0b, r0);
    CS_COMP(p1a, p1b, r1);
    CS_COMP(p2a, p2b, r2);
    CS_COMP(p3a, p3b, r3);
#undef CS_COMP
#undef CS_LOAD

    // Butterfly over the 4 row-groups -> lanes 0..15 hold colsum of col rg*16+l
    ca0 += __shfl_xor(ca0, 16); ca0 += __shfl_xor(ca0, 32);
    ca1 += __shfl_xor(ca1, 16); ca1 += __shfl_xor(ca1, 32);
    if (l < 16) { cs[w * 32 + l] = ca0; cs[w * 32 + 16 + l] = ca1; }
    __syncthreads();

    // out[m][d] = colsum[m] * v[m][d]  (128 rows x 64 d, float4-vectorized)
    const float4* Vg = (const float4*)(v + ((size_t)bh * N_ + cb * PNL) * D_);
    float4* Og = (float4*)(out + ((size_t)bh * N_ + cb * PNL) * D_);
    #pragma unroll
    for (int i = 0; i < 8; ++i) {
        int id = i * 256 + t;                // 2048 float4 units
        float s = cs[id >> 4];
        float4 vv = Vg[id];
        float4 o; o.x = vv.x * s; o.y = vv.y * s; o.z = vv.z * s; o.w = vv.w * s;
        Og[id] = o;
    }
}

// ===========================================================================
// Fallback (R2 path) if ws_size is too small for the bf16 staging buffers.
// ===========================================================================
#define FTS 128
#define FNT 16

__device__ __forceinline__ bf16x8 cvt8(const float* p) {
    float4 a = *(const float4*)p;
    float4 b = *(const float4*)(p + 4);
    bf16x8 r;
    r[0] = f2bf(a.x); r[1] = f2bf(a.y); r[2] = f2bf(a.z); r[3] = f2bf(a.w);
    r[4] = f2bf(b.x); r[5] = f2bf(b.y); r[6] = f2bf(b.z); r[7] = f2bf(b.w);
    return r;
}
__device__ __forceinline__ void fstage(char* lds, const float* src, int t) {
    #pragma unroll
    for (int i = 0; i < 2; ++i) {
        int ch = i * 512 + t, r = ch >> 3, cc = ch & 7;
        bf16x8 v = cvt8(src + (size_t)r * D_ + cc * 8);
        *(bf16x8*)(lds + r * 128 + ((cc ^ (r & 7)) << 4)) = v;
    }
}
__device__ __forceinline__ bf16x8 fread(const char* lds, int row, int cc) {
    return *(const bf16x8*)(lds + row * 128 + ((cc ^ (row & 7)) << 4));
}

__global__ __launch_bounds__(512)
void mha_rowsum_fb(const float* __restrict__ q, const float* __restrict__ k,
                   float* __restrict__ rinv)
{
    __shared__ __align__(16) char KT[FTS * 128];
    const int t = threadIdx.x, w = t >> 6, l = t & 63;
    const int bh = blockIdx.x / FNT, rb = blockIdx.x % FNT;
    const float* Qg = q + (size_t)bh * N_ * D_;
    const float* Kg = k + (size_t)bh * N_ * D_;
    const int qrow = rb * FTS + w * 16 + (l & 15);
    bf16x8 af[2];
    #pragma unroll
    for (int kh = 0; kh < 2; ++kh)
        af[kh] = cvt8(Qg + (size_t)qrow * D_ + kh * 32 + (l >> 4) * 8);
    float rs[4] = {0.f, 0.f, 0.f, 0.f};
    for (int ct = 0; ct < FNT; ++ct) {
        __syncthreads();
        fstage(KT, Kg + (size_t)ct * FTS * D_, t);
        __syncthreads();
        #pragma unroll
        for (int cj = 0; cj < 8; ++cj) {
            const int krow = cj * 16 + (l & 15);
            f32x4 c = {0.f, 0.f, 0.f, 0.f};
            #pragma unroll
            for (int kh = 0; kh < 2; ++kh)
                c = __builtin_amdgcn_mfma_f32_16x16x32_bf16(af[kh], fread(KT, krow, kh * 4 + (l >> 4)), c, 0, 0, 0);
            rs[0] += __expf(c[0] * SCALE); rs[1] += __expf(c[1] * SCALE);
            rs[2] += __expf(c[2] * SCALE); rs[3] += __expf(c[3] * SCALE);
        }
    }
    #pragma unroll
    for (int i = 0; i < 4; ++i) {
        rs[i] += __shfl_xor(rs[i], 1); rs[i] += __shfl_xor(rs[i], 2);
        rs[i] += __shfl_xor(rs[i], 4); rs[i] += __shfl_xor(rs[i], 8);
    }
    if ((l & 15) == 0) {
        const int rbase = rb * FTS + w * 16 + (l >> 4) * 4;
        #pragma unroll
        for (int i = 0; i < 4; ++i)
            rinv[(size_t)bh * N_ + rbase + i] = 1.0f / rs[i];
    }
}

__global__ __launch_bounds__(512)
void mha_colsum_fb(const float* __restrict__ q, const float* __restrict__ k,
                   const float* __restrict__ v, const float* __restrict__ rinv,
                   float* __restrict__ out)
{
    __shared__ __align__(16) char QT[FTS * 128];
    __shared__ float rv[FTS];
    __shared__ float cs2[FTS];
    const int t = threadIdx.x, w = t >> 6, l = t & 63;
    const int bh = blockIdx.x / FNT, cb = blockIdx.x % FNT;
    const float* Qg = q + (size_t)bh * N_ * D_;
    const float* Kg = k + (size_t)bh * N_ * D_;
    const float* Rg = rinv + (size_t)bh * N_;
    const int kcol = cb * FTS + w * 16 + (l & 15);
    bf16x8 kf[2];
    #pragma unroll
    for (int kh = 0; kh < 2; ++kh)
        kf[kh] = cvt8(Kg + (size_t)kcol * D_ + kh * 32 + (l >> 4) * 8);
    float ca = 0.f;
    for (int rt = 0; rt < FNT; ++rt) {
        __syncthreads();
        fstage(QT, Qg + (size_t)rt * FTS * D_, t);
        if (t < FTS) rv[t] = Rg[rt * FTS + t];
        __syncthreads();
        #pragma unroll
        for (int rj = 0; rj < 8; ++rj) {
            const int qr = rj * 16 + (l & 15);
            f32x4 c = {0.f, 0.f, 0.f, 0.f};
            #pragma unroll
            for (int kh = 0; kh < 2; ++kh)
                c = __builtin_amdgcn_mfma_f32_16x16x32_bf16(fread(QT, qr, kh * 4 + (l >> 4)), kf[kh], c, 0, 0, 0);
            float4 r4 = *(const float4*)&rv[rj * 16 + (l >> 4) * 4];
            ca += __expf(c[0] * SCALE) * r4.x + __expf(c[1] * SCALE) * r4.y
                + __expf(c[2] * SCALE) * r4.z + __expf(c[3] * SCALE) * r4.w;
        }
    }
    ca += __shfl_xor(ca, 16); ca += __shfl_xor(ca, 32);
    if (l < 16) cs2[w * 16 + l] = ca;
    __syncthreads();
    const float4* Vg = (const float4*)(v + (size_t)bh * N_ * D_ + (size_t)cb * FTS * D_);
    float4* Og = (float4*)(out + (size_t)bh * N_ * D_ + (size_t)cb * FTS * D_);
    #pragma unroll
    for (int i = 0; i < 4; ++i) {
        int id = i * 512 + t;
        float s = cs2[id >> 4];
        float4 vv = Vg[id];
        float4 o; o.x = vv.x * s; o.y = vv.y * s; o.z = vv.z * s; o.w = vv.w * s;
        Og[id] = o;
    }
}

// ---------------------------------------------------------------------------
extern "C" void kernel_launch(void* const* d_in, const int* in_sizes, int n_in,
                              void* d_out, int out_size, void* d_ws, size_t ws_size,
                              hipStream_t stream)
{
    const float* q = (const float*)d_in[0];
    const float* k = (const float*)d_in[1];
    const float* v = (const float*)d_in[2];
    float* out = (float*)d_out;

    const size_t need = QKB + (size_t)BH_ * N_ * 4;        // image + rinv

    if (ws_size >= need) {
        char*  qk   = (char*)d_ws;
        float* rinv = (float*)(qk + QKB);
        mha_convert<<<dim3(2 * BH_ * N_ * 8 / 512), dim3(512), 0, stream>>>(q, k, qk);
        mha_rowsum9<<<dim3(BH_ * NPN), dim3(256), 0, stream>>>(qk, rinv);
        mha_colsum9<<<dim3(BH_ * NPN), dim3(256), 0, stream>>>(qk, rinv, v, out);
    } else {
        float* rinv = (float*)d_ws;
        mha_rowsum_fb<<<dim3(BH_ * FNT), dim3(512), 0, stream>>>(q, k, rinv);
        mha_colsum_fb<<<dim3(BH_ * FNT), dim3(512), 0, stream>>>(q, k, v, rinv, out);
    }
}